// Round 10
// baseline (32.624 us; speedup 1.0000x reference)
//
#include <hip/hip_runtime.h>

// ConvNeXtLoss: fused attention-BCE + dice + reverse-dice over (16,4,512,512).
// Pass 1: m97/T3-style 2-phase double-buffered global_load_lds pipeline.
//         Each block owns 4 CONSECUTIVE 2048-elem tiles (one plane); per
//         iteration: STAGE(next buf) -> compute(cur buf) -> __syncthreads()
//         (vmcnt(0) drain AFTER compute, so DMA hides under the math).
// Pass 2: parallel finalize (R9-validated), adapted to 32 blocks/plane.
// No fences/atomics (R5/R6: per-block __threadfence = 10x regression).
//
// R10 vs R9 (31.2 us; main ~29.5): R9's single-shot blocks had ~40% DMA
// duty cycle + one cold DMA latency per 16 KB. Grid-stride dbuf keeps a
// 16 KB STAGE in flight through every compute phase and amortizes the
// cold start over 64 KB.

typedef float f32x4 __attribute__((ext_vector_type(4)));
typedef int   i32x4 __attribute__((ext_vector_type(4)));

#define B_DIM 16
#define C_DIM 4
#define HW 262144                 // 512*512 plane
#define NPLANES 64                // B*C
#define NTHREADS 128
#define NWAVES (NTHREADS / 64)    // 2
#define TILE 2048                 // elems per tile
#define TILES 4                   // tiles per block (consecutive!)
#define NBLOCKS 2048              // 2048*4*2048 = 16.78M elems
#define BPP 32                    // blocks per plane = HW/(TILE*TILES)
#define NSUMS 6
#define WELEMS (TILE / NWAVES)    // 1024 elems per wave per tile
#define WOPS (WELEMS / 256)       // 4 DMA rounds per array per wave

__global__ __launch_bounds__(NTHREADS) void loss_main(
    const float* __restrict__ pred, const int* __restrict__ label,
    float* __restrict__ ws) {
  __shared__ float sp[2][TILE];   // 16 KB (two 8 KB buffers)
  __shared__ int   st[2][TILE];   // 16 KB
  __shared__ float red[NWAVES][NSUMS];

  const int block = blockIdx.x;          // 0..2047
  const int tid = threadIdx.x;
  const int w = tid >> 6, l = tid & 63;
  const long base0 = (long)block * (TILE * TILES);
  const float* gp = pred + base0 + w * WELEMS;
  const int*   gt = label + base0 + w * WELEMS;

  // STAGE(tile t into buffer c): 8 async DMA ops per wave, 16B/lane,
  // wave-uniform LDS dest (c, w, r all compile-time/uniform).
#define STAGE(c, t)                                                          \
  _Pragma("unroll")                                                          \
  for (int r = 0; r < WOPS; ++r) {                                           \
    __builtin_amdgcn_global_load_lds(                                        \
        (const __attribute__((address_space(1))) void*)(gp + (t) * TILE +    \
                                                        r * 256 + l * 4),    \
        (__attribute__((address_space(3))) void*)(&sp[c][w * WELEMS +        \
                                                         r * 256]),          \
        16, 0, 0);                                                           \
    __builtin_amdgcn_global_load_lds(                                        \
        (const __attribute__((address_space(1))) void*)(gt + (t) * TILE +    \
                                                        r * 256 + l * 4),    \
        (__attribute__((address_space(3))) void*)(&st[c][w * WELEMS +        \
                                                         r * 256]),          \
        16, 0, 0);                                                           \
  }

  float s_pt = 0.f, s_pp = 0.f, s_p = 0.f;
  float nsum_t = 0.f;   // sum over ALL elems of Bw * (-L)
  float nsum_1 = 0.f;   // sum over t==1 elems of Bw * (-L)
  int   s_ti = 0;       // integer count of positives

#define COMPUTE(c)                                                           \
  _Pragma("unroll")                                                          \
  for (int r = 0; r < WOPS; ++r) {                                           \
    f32x4 P = *(const f32x4*)&sp[c][w * WELEMS + r * 256 + l * 4];           \
    i32x4 T = *(const i32x4*)&st[c][w * WELEMS + r * 256 + l * 4];           \
    _Pragma("unroll")                                                        \
    for (int j = 0; j < 4; ++j) {                                            \
      float pv = P[j];                                                       \
      float tf = (float)T[j];                       /* labels 0/1 */         \
      float u   = __builtin_fmaf(tf, -2.0f, 1.0f);  /* 1-2t */               \
      float arg = __builtin_fmaf(pv, u, tf);        /* t ? p : 1-p */        \
      float x   = 1.0f - arg;                       /* t ? 1-p : p */        \
      float r_  = __builtin_amdgcn_sqrtf(x);                                 \
      float Bw  = __builtin_amdgcn_exp2f(3.0f * r_);/* 8^sqrt(x) */          \
      float lg  = __builtin_amdgcn_logf(arg);       /* log2 */               \
      float L   = fmaxf(0.69314718056f * lg, -100.0f);                       \
      float cc  = Bw * (-L);                                                 \
      nsum_t += cc;                                                          \
      nsum_1  = __builtin_fmaf(tf, cc, nsum_1);                              \
      s_pt    = __builtin_fmaf(tf, pv, s_pt);                                \
      s_pp    = __builtin_fmaf(pv, pv, s_pp);                                \
      s_p    += pv;                                                          \
      s_ti   += T[j];                                                        \
    }                                                                        \
  }

  // ---- 2-phase pipeline: STAGE(next) before COMPUTE(cur), 1 barrier/tile
  STAGE(0, 0)
  __syncthreads();            // tile 0 ready (cold start, once per block)
#pragma unroll
  for (int t = 0; t < TILES; ++t) {
    const int cur = t & 1;
    if (t + 1 < TILES) { STAGE(cur ^ 1, t + 1) }  // in flight during compute
    COMPUTE(cur)
    __syncthreads();          // vmcnt(0)+barrier AFTER compute: drain residual
  }

#undef STAGE
#undef COMPUTE

  float s_t = (float)s_ti;

  // wave reduce (64 lanes), then cross-wave via LDS
  float vals[NSUMS] = {s_pt, s_pp, s_t, s_p, nsum_1, nsum_t};
#pragma unroll
  for (int q = 0; q < NSUMS; ++q) {
    float v = vals[q];
#pragma unroll
    for (int off = 32; off; off >>= 1) v += __shfl_down(v, off);
    vals[q] = v;
  }
  if (l == 0) {
#pragma unroll
    for (int q = 0; q < NSUMS; ++q) red[w][q] = vals[q];
  }
  __syncthreads();
  if (tid < NSUMS) {
    float v = 0.f;
#pragma unroll
    for (int ww = 0; ww < NWAVES; ++ww) v += red[ww][tid];
    ws[block * NSUMS + tid] = v;
  }
}

// Parallel finalize: 1 block x 1024 threads, 16 threads per plane.
// Plane strip = 32 blocks x 6 = 192 floats; each thread reads 12 floats
// (3 x float4, q pattern compile-time), shfl_xor 16-lane group reduce.
__global__ __launch_bounds__(1024) void loss_finalize(
    const float* __restrict__ ws, float* __restrict__ out) {
  __shared__ float ps[NPLANES][NSUMS];
  const int tid = threadIdx.x;
  const int p = tid >> 4;       // plane 0..63
  const int s = tid & 15;       // sub-slice 0..15

  float acc[NSUMS] = {0.f, 0.f, 0.f, 0.f, 0.f, 0.f};
  const f32x4* base = (const f32x4*)(ws + (long)p * (BPP * NSUMS) + s * 12);
#pragma unroll
  for (int i = 0; i < 3; ++i) {
    f32x4 v = base[i];
#pragma unroll
    for (int j = 0; j < 4; ++j) acc[(i * 4 + j) % 6] += v[j];
  }
#pragma unroll
  for (int q = 0; q < NSUMS; ++q) {
    float v = acc[q];
    v += __shfl_xor(v, 1);
    v += __shfl_xor(v, 2);
    v += __shfl_xor(v, 4);
    v += __shfl_xor(v, 8);
    acc[q] = v;
  }
  if (s == 0) {
#pragma unroll
    for (int q = 0; q < NSUMS; ++q) ps[p][q] = acc[q];
  }
  __syncthreads();

  if (tid < 64) {
    const int pl = tid;        // plane index; b = pl>>2, c = pl&3
    const float s_pt = ps[pl][0], s_pp = ps[pl][1], s_t = ps[pl][2],
                s_p = ps[pl][3];
    const float sum1 = ps[pl][4];             // t==1 part
    const float sum2 = ps[pl][5] - ps[pl][4]; // t==0 part
    const float N = (float)HW;
    const float SM = 1e-6f;

    float dice = 1.0f - (2.0f * s_pt + SM) / (s_pp + s_t + SM);
    float inter2 = N - s_p - s_t + s_pt;
    float denom2 = 2.0f * N - 2.0f * s_p + s_pp - s_t;
    float rdice = 1.0f - (2.0f * inter2 + SM) / (denom2 + SM);

    float np4 = s_t + __shfl_xor(s_t, 1);
    np4 += __shfl_xor(np4, 2);
    const float total = (float)(C_DIM * HW);  // 1048576
    float alpha = (total - np4) / total;

    float val = alpha * sum1 + (1.0f - alpha) * sum2
              + 2500.0f * (dice + rdice);   // DICE_COEFF == REV_DICE_COEFF

#pragma unroll
    for (int off = 32; off; off >>= 1) val += __shfl_down(val, off);
    if (pl == 0) out[0] = val;
  }
}

extern "C" void kernel_launch(void* const* d_in, const int* in_sizes, int n_in,
                              void* d_out, int out_size, void* d_ws, size_t ws_size,
                              hipStream_t stream) {
  const float* pred = (const float*)d_in[0];
  const int* label = (const int*)d_in[1];
  float* out = (float*)d_out;
  float* ws = (float*)d_ws;  // needs NBLOCKS*NSUMS*4 = 48 KiB

  loss_main<<<NBLOCKS, NTHREADS, 0, stream>>>(pred, label, ws);
  loss_finalize<<<1, 1024, 0, stream>>>(ws, out);
}